// Round 9
// baseline (285.775 us; speedup 1.0000x reference)
//
#include <hip/hip_runtime.h>

#define NTOK 32768
#define TSTRIP 98304   // 768 chans * 128 toks per qkv strip-tile
#define TT 128         // tokens per transpose block

typedef __attribute__((ext_vector_type(8))) short  bf16x8;
typedef __attribute__((ext_vector_type(8))) unsigned short u16x8;
typedef __attribute__((ext_vector_type(4))) float  f32x4;

__device__ __forceinline__ unsigned short f32_to_bf16(float f) {
    unsigned int u = __float_as_uint(f);
    u += 0x7FFFu + ((u >> 16) & 1u);          // round-to-nearest-even
    return (unsigned short)(u >> 16);
}
__device__ __forceinline__ float bf16_to_f32(unsigned short h) {
    return __uint_as_float(((unsigned int)h) << 16);
}

// ---------------------------------------------------------------------------
// Streaming transpose + cast: x[b][256 c][32768 t] fp32 -> xT[b][t][c] bf16.
// Round-9 rationale: 8 rounds of nulls on gemm1 while it reads x as 131k
// scattered 256B segments at 128KB stride (DRAM small-request wall, pinned
// ~1.05 TB/s). This kernel reads x with 512B-contiguous float4 rows and
// writes xT fully contiguous (4KB per instruction), via an LDS tile.
// LDS xs[chan][tok] pitch 134 (67 dwords, odd -> adjacent rows on disjoint
// banks). Phase 2 gathers 8 chans/chunk (scalar b16 reads, bounded conflict)
// and stores 16B chunks raster-ordered -> consecutive lanes contiguous.
// ---------------------------------------------------------------------------
__global__ __launch_bounds__(256) void transpose_kernel(
    const float* __restrict__ x, unsigned short* __restrict__ xT)
{
    const int b = blockIdx.y;
    const int t0 = blockIdx.x * TT;
    const float* xb = x + (long)b * 256 * NTOK;
    unsigned short* ob = xT + ((long)b * NTOK + t0) * 256;

    __shared__ unsigned short xs[256 * 134];   // [chan][tok], ~68.6 KB

    const int tid = threadIdx.x;
    const int l = tid & 31;        // token-quad lane
    const int r0 = tid >> 5;       // 0..7

    // phase 1: coalesced read (512B/row) + cast + LDS write (2-way banks)
    #pragma unroll 4
    for (int p = 0; p < 32; ++p) {
        const int c = r0 + 8 * p;                      // adjacent rows per half-wave
        const float4 v = *(const float4*)&xb[(long)c * NTOK + t0 + 4 * l];
        ushort4 o;
        o.x = f32_to_bf16(v.x); o.y = f32_to_bf16(v.y);
        o.z = f32_to_bf16(v.z); o.w = f32_to_bf16(v.w);
        *(ushort4*)&xs[c * 134 + 4 * l] = o;
    }
    __syncthreads();

    // phase 2: transpose-gather + fully-contiguous global store
    #pragma unroll 4
    for (int j = 0; j < 16; ++j) {
        const int chunk = tid + 256 * j;               // 4096 16B chunks
        const int t = chunk >> 5;
        const int c0 = (chunk & 31) * 8;
        unsigned short o[8];
        #pragma unroll
        for (int i = 0; i < 8; ++i) o[i] = xs[(c0 + i) * 134 + t];
        *(u16x8*)&ob[(size_t)t * 256 + c0] = *(const u16x8*)o;
    }
}

// ---------------------------------------------------------------------------
// B-stationary MFMA GEMM: C[M,NTOK] = A[M,256] * B[256,NTOK].
// Geometry: round-1 proven (128-col strip/block, 64KB Bs, 4 waves 64x64).
// BMODE selects the B-tile source layout:
//   1 = strip-tiled k-major rows of 128 toks (qkv_t; gemm2)
//   2 = tok-major [tok][256 chan] (xT; gemm1) -> staging is a CONTIGUOUS
//       64KB copy: 16B load + swizzled 16B ds_write, no conversion.
// CTILED: C strip-tiled (qkv_t) vs flat (out).
// MFMA operands SWAPPED (bf as A-operand) -> lane row(chan)=m16 fixed, cols
// quad*4+r consecutive -> ushort4/float4 stores. A-fragments from global
// (L2-resident) with 1-deep register prefetch. QSOFT: softmax over m16 lanes.
// ---------------------------------------------------------------------------
template <typename BT, typename CT, int MCHUNKS, bool QSOFT, int BMODE, bool CTILED>
__global__ __launch_bounds__(256) void gemm_bstat(
    const unsigned short* __restrict__ A, const BT* __restrict__ B,
    CT* __restrict__ C, long sA, long sB, long sC)
{
    const int bz = blockIdx.y;
    A += (long)bz * sA; B += (long)bz * sB; C += (long)bz * sC;
    const int strip = blockIdx.x;
    const int col0 = strip * 128;

    CT* Cbase = CTILED ? C + (size_t)strip * TSTRIP : C + col0;
    const long cstride = CTILED ? 128 : NTOK;

    __shared__ unsigned short Bs[128 * 256];   // 64 KB

    const int t = threadIdx.x;
    const int wave = t >> 6, lane = t & 63;
    const int wm = wave >> 1, wn = wave & 1;
    const int m16 = lane & 15, quad = lane >> 4;

    // ---- stage B tile once -> Bs[n][256k] bf16 (16B-granule XOR swizzle)
    {
        const int n = t & 127;                  // tok within strip
        const int kg0 = (t >> 7) * 16;          // k-half
        const int key = n & 7;
        if constexpr (BMODE == 2) {
            // xT: [tok][256 chan] bf16, strip tile contiguous 64KB
            const unsigned short* Bt =
                (const unsigned short*)B + (size_t)strip * (128 * 256) + n * 256;
            #pragma unroll
            for (int g = 0; g < 16; ++g) {
                const int kg = kg0 + g;
                *(u16x8*)&Bs[n * 256 + ((kg ^ key) * 8)] =
                    *(const u16x8*)&Bt[kg * 8];
            }
        } else {
            // qkv_t: strip tile, k-major rows of 128 toks
            const BT* bcol = B + (size_t)strip * TSTRIP + n;
            #pragma unroll
            for (int g = 0; g < 16; ++g) {
                const int kg = kg0 + g;
                unsigned short tmp[8];
                #pragma unroll
                for (int i = 0; i < 8; ++i) {
                    BT v = bcol[(size_t)(kg * 8 + i) * 128];
                    if constexpr (sizeof(BT) == 4) tmp[i] = f32_to_bf16((float)v);
                    else                           tmp[i] = (unsigned short)v;
                }
                *(u16x8*)&Bs[n * 256 + ((kg ^ key) * 8)] = *(const u16x8*)tmp;
            }
        }
    }
    __syncthreads();   // the only barrier

    const int swk = m16 & 7;

    for (int mc = 0; mc < MCHUNKS; ++mc) {
        const int m0 = mc * 128;
        f32x4 acc[4][4] = {};

        const unsigned short* Abase = A + (size_t)(m0 + wm * 64 + m16) * 256 + quad * 8;

        bf16x8 af_cur[4], af_nxt[4];
        #pragma unroll
        for (int mt = 0; mt < 4; ++mt)
            af_cur[mt] = *(const bf16x8*)&Abase[(size_t)mt * 16 * 256];

        #pragma unroll
        for (int kk = 0; kk < 8; ++kk) {
            if (kk < 7) {
                #pragma unroll
                for (int mt = 0; mt < 4; ++mt)
                    af_nxt[mt] = *(const bf16x8*)
                        &Abase[(size_t)mt * 16 * 256 + (kk + 1) * 32];
            }

            bf16x8 bf[4];
            #pragma unroll
            for (int nt = 0; nt < 4; ++nt) {
                const int col = wn * 64 + nt * 16 + m16;
                bf[nt] = *(const bf16x8*)&Bs[col * 256 + (((kk * 4 + quad) ^ swk) * 8)];
            }
            #pragma unroll
            for (int mt = 0; mt < 4; ++mt)
                #pragma unroll
                for (int nt = 0; nt < 4; ++nt)
                    acc[mt][nt] = __builtin_amdgcn_mfma_f32_16x16x32_bf16(
                        bf[nt], af_cur[mt], acc[mt][nt], 0, 0, 0);  // SWAPPED

            #pragma unroll
            for (int mt = 0; mt < 4; ++mt) af_cur[mt] = af_nxt[mt];
        }

        // ---- fused q softmax: mt pairs (0,1),(2,3) are heads; chan=mt*16+m16
        if (QSOFT && m0 < 256) {
            #pragma unroll
            for (int hj = 0; hj < 2; ++hj) {
                #pragma unroll
                for (int nt = 0; nt < 4; ++nt) {
                    #pragma unroll
                    for (int r = 0; r < 4; ++r) {
                        float mx = fmaxf(acc[hj * 2][nt][r], acc[hj * 2 + 1][nt][r]);
                        mx = fmaxf(mx, __shfl_xor(mx, 1, 64));
                        mx = fmaxf(mx, __shfl_xor(mx, 2, 64));
                        mx = fmaxf(mx, __shfl_xor(mx, 4, 64));
                        mx = fmaxf(mx, __shfl_xor(mx, 8, 64));
                        const float e0 = __expf(acc[hj * 2][nt][r] - mx);
                        const float e1 = __expf(acc[hj * 2 + 1][nt][r] - mx);
                        float s = e0 + e1;
                        s += __shfl_xor(s, 1, 64);
                        s += __shfl_xor(s, 2, 64);
                        s += __shfl_xor(s, 4, 64);
                        s += __shfl_xor(s, 8, 64);
                        const float inv = 1.0f / s;
                        acc[hj * 2][nt][r]     = e0 * inv;
                        acc[hj * 2 + 1][nt][r] = e1 * inv;
                    }
                }
            }
        }

        // ---- store: lane holds row(chan)=mt*16+m16, 4 consecutive local cols
        #pragma unroll
        for (int mt = 0; mt < 4; ++mt) {
            const int row = m0 + wm * 64 + mt * 16 + m16;
            #pragma unroll
            for (int nt = 0; nt < 4; ++nt) {
                const int col = wn * 64 + nt * 16 + quad * 4;   // local 0..127
                if constexpr (sizeof(CT) == 4) {
                    *(float4*)&Cbase[(size_t)row * cstride + col] =
                        *(const float4*)&acc[mt][nt];
                } else {
                    ushort4 o;
                    o.x = f32_to_bf16(acc[mt][nt][0]);
                    o.y = f32_to_bf16(acc[mt][nt][1]);
                    o.z = f32_to_bf16(acc[mt][nt][2]);
                    o.w = f32_to_bf16(acc[mt][nt][3]);
                    *(ushort4*)&Cbase[(size_t)row * cstride + col] = o;
                }
            }
        }
    }
}

// ---------------------------------------------------------------------------
// fp32 -> bf16 cast (vectorized)
// ---------------------------------------------------------------------------
__global__ __launch_bounds__(256) void cast_bf16_kernel(
    const float* __restrict__ src, unsigned short* __restrict__ dst, int n4)
{
    const int i = blockIdx.x * 256 + threadIdx.x;
    if (i < n4) {
        float4 v = ((const float4*)src)[i];
        ushort4 o;
        o.x = f32_to_bf16(v.x); o.y = f32_to_bf16(v.y);
        o.z = f32_to_bf16(v.z); o.w = f32_to_bf16(v.w);
        ((ushort4*)dst)[i] = o;
    }
}

// ---------------------------------------------------------------------------
// MFMA-based context on the STRIP-TILED qkv: num[b,h,d,e] += exp(k)*v.
// ---------------------------------------------------------------------------
__global__ __launch_bounds__(512) void ctx_mfma_kernel(
    const unsigned short* __restrict__ qkv,
    float* __restrict__ num, float* __restrict__ den)
{
    const int b = blockIdx.y;
    const int s0 = blockIdx.x * 2;            // 2 strips per block
    const int h = threadIdx.x >> 6;           // wave id == head id
    const int lane = threadIdx.x & 63;
    const int m16 = lane & 15, quad = lane >> 4;

    const unsigned short* base = qkv + (long)b * 768 * NTOK;

    f32x4 acc[2][2] = {};       // [dtile][etile]
    float dp[2] = {0.f, 0.f};   // den partials

    #pragma unroll
    for (int st = 0; st < 2; ++st) {
        const unsigned short* tile = base + (size_t)(s0 + st) * TSTRIP;
        const unsigned short* kp = tile + (256 + h * 32 + m16) * 128 + quad * 8;
        const unsigned short* vp = tile + (512 + h * 32 + m16) * 128 + quad * 8;
        #pragma unroll
        for (int kg = 0; kg < 4; ++kg) {
            const int off = kg * 32;
            bf16x8 af[2], bfv[2];
            #pragma unroll
            for (int dt = 0; dt < 2; ++dt) {
                const u16x8 kr = *(const u16x8*)(kp + dt * 2048 + off);
                unsigned short tmp[8];
                #pragma unroll
                for (int i = 0; i < 8; ++i) {
                    const float e = __expf(bf16_to_f32(kr[i]));
                    const unsigned short eb = f32_to_bf16(e);
                    tmp[i] = eb;
                    dp[dt] += bf16_to_f32(eb);
                }
                af[dt] = *(const bf16x8*)tmp;
            }
            #pragma unroll
            for (int et = 0; et < 2; ++et)
                bfv[et] = *(const bf16x8*)(vp + et * 2048 + off);
            #pragma unroll
            for (int dt = 0; dt < 2; ++dt)
                #pragma unroll
                for (int et = 0; et < 2; ++et)
                    acc[dt][et] = __builtin_amdgcn_mfma_f32_16x16x32_bf16(
                        af[dt], bfv[et], acc[dt][et], 0, 0, 0);
        }
    }

    float* nbase = num + ((long)(b * 8 + h) * 32) * 32;
    #pragma unroll
    for (int dt = 0; dt < 2; ++dt)
        #pragma unroll
        for (int et = 0; et < 2; ++et)
            #pragma unroll
            for (int r = 0; r < 4; ++r)
                atomicAdd(&nbase[(dt * 16 + quad * 4 + r) * 32 + et * 16 + m16],
                          acc[dt][et][r]);

    #pragma unroll
    for (int dt = 0; dt < 2; ++dt) {
        float s = dp[dt];
        s += __shfl_xor(s, 16, 64);
        s += __shfl_xor(s, 32, 64);
        if (quad == 0)
            atomicAdd(&den[b * 256 + h * 32 + dt * 16 + m16], s);
    }
}

// ---------------------------------------------------------------------------
// W2[b][o][h*32+d] = (sum_e w_out[o,h*32+e] * num[b,h,d,e]) / den[b,h*32+d]
// ---------------------------------------------------------------------------
__global__ __launch_bounds__(256) void combine_kernel(
    const float* __restrict__ w_out, const float* __restrict__ num,
    const float* __restrict__ den, unsigned short* __restrict__ W2)
{
    const int tid = blockIdx.x * 256 + threadIdx.x;   // 2*256*256 total
    const int b = tid >> 16;
    const int rem = tid & 65535;
    const int o = rem >> 8;
    const int i = rem & 255;
    const int h = i >> 5, d = i & 31;
    const float* wrow = w_out + o * 256 + h * 32;
    const float* nrow = num + (((long)(b * 8 + h) * 32 + d) << 5);
    float s = 0.f;
    #pragma unroll
    for (int e = 0; e < 32; ++e) s += wrow[e] * nrow[e];
    W2[tid] = f32_to_bf16(s / den[b * 256 + h * 32 + d]);
}

// ---------------------------------------------------------------------------
extern "C" void kernel_launch(void* const* d_in, const int* in_sizes, int n_in,
                              void* d_out, int out_size, void* d_ws, size_t ws_size,
                              hipStream_t stream)
{
    const float* x     = (const float*)d_in[0];   // [2,256,32768]
    const float* w_qkv = (const float*)d_in[1];   // [768,256]
    const float* w_out = (const float*)d_in[2];   // [256,256]
    float* out = (float*)d_out;                   // [2,256,32768]

    // workspace layout (qkv strip-tiled: [b][strip][768][128] bf16)
    unsigned short* qkv_bf = (unsigned short*)d_ws;           // 2*768*32768 bf16
    const long qkv_elems = 2L * 768 * NTOK;
    unsigned short* wqkv_bf = qkv_bf + qkv_elems;             // 768*256 bf16
    unsigned short* W2 = wqkv_bf + 768 * 256;                 // 2*256*256 bf16
    float* num  = (float*)(W2 + 2 * 256 * 256);               // 16384
    float* den  = num + 16384;                                // 512

    // xT scratch lives in d_out (32MB < 67MB; gemm2 fully overwrites out later)
    unsigned short* xT = (unsigned short*)d_out;              // [b][32768][256] bf16

    hipMemsetAsync(num, 0, (16384 + 512) * sizeof(float), stream);

    // 0) cast w_qkv to bf16
    cast_bf16_kernel<<<192, 256, 0, stream>>>(w_qkv, wqkv_bf, 768 * 256 / 4);

    // 0b) streaming transpose+cast: x -> xT[b][t][c] bf16
    transpose_kernel<<<dim3(NTOK / TT, 2), 256, 0, stream>>>(x, xT);

    // 1) qkv_t = w_qkv @ x (B = xT tok-major, C strip-tiled); q softmax fused
    gemm_bstat<unsigned short, unsigned short, 6, true, 2, true>
        <<<dim3(256, 2), 256, 0, stream>>>(
        wqkv_bf, xT, qkv_bf, 0L, (long)NTOK * 256, 768L * NTOK);

    // 2) context num/den via MFMA on tiled qkv
    ctx_mfma_kernel<<<dim3(NTOK / 256, 2), 512, 0, stream>>>(qkv_bf, num, den);

    // 3) W2 = fold(w_out, context) -> bf16
    combine_kernel<<<512, 256, 0, stream>>>(w_out, num, den, W2);

    // 4) out = W2 @ q_soft (B strip-tiled k-major, C flat fp32)
    gemm_bstat<unsigned short, float, 2, false, 1, false>
        <<<dim3(256, 2), 256, 0, stream>>>(
        W2, qkv_bf, out, 65536L, 768L * NTOK, 256L * NTOK);
}